// Round 5
// baseline (141.083 us; speedup 1.0000x reference)
//
#include <hip/hip_runtime.h>

// ProtoNet head: N=16384 rows, C=128 classes, D=1024 dims, fp32 in/out.
// out = softmax_c( 2*dot(e[n], cent[c]) - ||cent[c]||^2 )  (sq_e dropped: softmax shift-invariant)
// cross term via split-bf16 MFMA: x=hi+lo; x*c ~= hi*chi + hi*clo + lo*chi  (K'=3072 bf16)

#define N_ROWS 16384
#define N_CLS  128
#define N_DIM  1024
#define CSTRIDE 32   // pad atomics: one counter per 128B cache line

// workspace layout (bytes); need ~672 KiB total
#define CNT_OFF 0         // int cnt[128*32]     (16 KiB)
#define SQC_OFF 16384     // float sqc[128*32]   (16 KiB)
#define RL_OFF  32768     // int rowlist[128*256] (128 KiB)
#define BHI_OFF 163840    // bf16 B-frags hi: 32 steps*8 frags*64 lanes*8 = 256 KiB
#define BLO_OFF 425984    // bf16 B-frags lo: 256 KiB

typedef __attribute__((ext_vector_type(8))) short bf16x8;
typedef __attribute__((ext_vector_type(4))) float f32x4;

// ---------------- kernel 1: labels -> rowlist + padded counts ----------------
__global__ void k_label(const float* __restrict__ y,
                        int* __restrict__ cnt,
                        int* __restrict__ rowlist) {
    int i = blockIdx.x * blockDim.x + threadIdx.x;   // float4 index over N*C/4
    float4 v = ((const float4*)y)[i];
    int base = i * 4;
    int row = base >> 7;          // / C
    int cb  = base & (N_CLS - 1); // % C
    if (v.x > 0.5f) { int s = atomicAdd(&cnt[(cb + 0) * CSTRIDE], 1); if (s < 256) rowlist[(cb + 0) * 256 + s] = row; }
    if (v.y > 0.5f) { int s = atomicAdd(&cnt[(cb + 1) * CSTRIDE], 1); if (s < 256) rowlist[(cb + 1) * 256 + s] = row; }
    if (v.z > 0.5f) { int s = atomicAdd(&cnt[(cb + 2) * CSTRIDE], 1); if (s < 256) rowlist[(cb + 2) * 256 + s] = row; }
    if (v.w > 0.5f) { int s = atomicAdd(&cnt[(cb + 3) * CSTRIDE], 1); if (s < 256) rowlist[(cb + 3) * 256 + s] = row; }
}

// ---- kernel 2: centroids -> packed bf16 hi/lo B-fragments + sq_c ----
// grid (8 d-chunks, 128 classes), 128 threads; thread owns (class c, dim d).
// B-frag for mfma_f32_16x16x32_bf16: elem j of lane l, step gs, col-frag f
//   = B[k = gs*32 + (l>>4)*8 + j][col = f*16 + (l&15)]
__global__ void k_centroid(const float* __restrict__ e,
                           const int* __restrict__ cnt,
                           const int* __restrict__ rowlist,
                           unsigned short* __restrict__ bHi,
                           unsigned short* __restrict__ bLo,
                           float* __restrict__ sqc) {
    int c  = blockIdx.y;
    int ch = blockIdx.x;
    int t  = threadIdx.x;
    int d  = ch * 128 + t;
    int n  = cnt[c * CSTRIDE];
    if (n > 256) n = 256;
    const int* rl = rowlist + c * 256;

    float acc = 0.f;
    int i = 0;
    // 16-deep MLP: 32 KB/CU in flight vs ~9.4 KB needed at HBM latency
    for (; i + 16 <= n; i += 16) {
        float v[16];
        #pragma unroll
        for (int u = 0; u < 16; ++u) v[u] = e[(size_t)rl[i + u] * N_DIM + d];
        float s0 = ((v[0] + v[1]) + (v[2] + v[3])) + ((v[4] + v[5]) + (v[6] + v[7]));
        float s1 = ((v[8] + v[9]) + (v[10] + v[11])) + ((v[12] + v[13]) + (v[14] + v[15]));
        acc += s0 + s1;
    }
    for (; i < n; ++i) acc += e[(size_t)rl[i] * N_DIM + d];

    float val = (n > 0) ? acc / (float)n : 0.f;

    // split val = hi + lo (truncation split; the subtraction is exact)
    unsigned xb = __float_as_uint(val);
    unsigned short hv = (unsigned short)(xb >> 16);
    float hif = __uint_as_float(xb & 0xffff0000u);
    unsigned short lv = (unsigned short)(__float_as_uint(val - hif) >> 16);

    int gs = d >> 5;            // k-step
    int g  = (d >> 3) & 3;      // lane group
    int j  = d & 7;             // element within fragment
    int f  = c >> 4;            // col fragment
    int lb = g * 16 + (c & 15); // lane
    bHi[((gs * 8 + f) * 64 + lb) * 8 + j] = hv;
    bLo[((gs * 8 + f) * 64 + lb) * 8 + j] = lv;

    // ||centroid||^2 partial -> padded atomic (16 per class)
    float s = val * val;
    #pragma unroll
    for (int m = 1; m < 64; m <<= 1) s += __shfl_xor(s, m, 64);
    if ((t & 63) == 0) atomicAdd(&sqc[c * CSTRIDE], s);
}

// ------- kernel 3: split-bf16 MFMA GEMM + fused softmax --------
// 256 blocks x 256 thr (4 waves). Wave = K-quarter kq: 64 rows x 128 cols
// (4 row-frags x 8 col-frags), 8 steps of 32 fp32-k. 96 MFMA per step
// (~460 cyc shadow) vs 24 independent loads -> latency hidden even with
// conservative compiler scheduling. K-combine: two-phase 64 KiB LDS
// reduction; wave kq finishes 16-row chunk kq with fused softmax.
__device__ __forceinline__ void split8(const float4 a0, const float4 a1,
                                       bf16x8& hi, bf16x8& lo) {
    float v[8] = {a0.x, a0.y, a0.z, a0.w, a1.x, a1.y, a1.z, a1.w};
    #pragma unroll
    for (int j = 0; j < 8; ++j) {
        unsigned xb = __float_as_uint(v[j]);
        hi[j] = (short)(xb >> 16);
        float hif = __uint_as_float(xb & 0xffff0000u);
        lo[j] = (short)(__float_as_uint(v[j] - hif) >> 16);
    }
}

__launch_bounds__(256, 1)
__global__ void k_gemm(const float* __restrict__ e,
                       const unsigned short* __restrict__ bHiU,
                       const unsigned short* __restrict__ bLoU,
                       const float* __restrict__ sqc,
                       float* __restrict__ out) {
    __shared__ f32x4 L[4][2][8][64];   // 64 KiB: [kq][m-chunk][f][lane]

    const bf16x8* bHi = (const bf16x8*)bHiU;
    const bf16x8* bLo = (const bf16x8*)bLoU;

    int tid  = threadIdx.x;
    int lane = tid & 63;
    int kq   = tid >> 6;        // K-quarter 0..3
    int row0 = blockIdx.x * 64;
    int rlo  = lane & 15;
    int g    = lane >> 4;

    f32x4 acc[4][8];
    #pragma unroll
    for (int m = 0; m < 4; ++m)
        #pragma unroll
        for (int f = 0; f < 8; ++f)
            acc[m][f] = (f32x4)(0.f);

    #pragma unroll
    for (int s = 0; s < 8; ++s) {
        int gs = kq * 8 + s;

        // B fragments for all 128 cols at this step (L2-resident, 768 KiB/XCD)
        bf16x8 bh[8], bl[8];
        #pragma unroll
        for (int f = 0; f < 8; ++f) {
            int bi = (gs * 8 + f) * 64 + lane;
            bh[f] = bHi[bi];
            bl[f] = bLo[bi];
        }

        // A fp32 in fragment layout (4 row-frags), split hi/lo in-reg
        bf16x8 ah[4], al[4];
        #pragma unroll
        for (int m = 0; m < 4; ++m) {
            const float* ap = e + (size_t)(row0 + m * 16 + rlo) * N_DIM + gs * 32 + g * 8;
            float4 a0 = *(const float4*)ap;
            float4 a1 = *(const float4*)(ap + 4);
            split8(a0, a1, ah[m], al[m]);
        }

        // 96 MFMA: the fat shadow
        #pragma unroll
        for (int f = 0; f < 8; ++f)
            #pragma unroll
            for (int m = 0; m < 4; ++m) {
                acc[m][f] = __builtin_amdgcn_mfma_f32_16x16x32_bf16(ah[m], bh[f], acc[m][f], 0, 0, 0);
                acc[m][f] = __builtin_amdgcn_mfma_f32_16x16x32_bf16(ah[m], bl[f], acc[m][f], 0, 0, 0);
                acc[m][f] = __builtin_amdgcn_mfma_f32_16x16x32_bf16(al[m], bh[f], acc[m][f], 0, 0, 0);
            }
    }

    // sq_c for my 8 col-frags
    float sq[8];
    #pragma unroll
    for (int f = 0; f < 8; ++f) sq[f] = sqc[(f * 16 + rlo) * CSTRIDE];

    // two-phase K-combine (64 KiB LDS) + fused softmax.
    // phase p covers m-chunks {2p, 2p+1}; wave kq finishes m-chunk kq.
    #pragma unroll
    for (int p = 0; p < 2; ++p) {
        __syncthreads();   // phase 0: plain entry sync; phase 1: protect re-dump
        #pragma unroll
        for (int mm = 0; mm < 2; ++mm)
            #pragma unroll
            for (int f = 0; f < 8; ++f)
                L[kq][mm][f][lane] = acc[p * 2 + mm][f];
        __syncthreads();

        int c = kq - p * 2;
        if (c >= 0 && c < 2) {
            // sum the 4 K-quarter partials for m-chunk (p*2+c)
            f32x4 r[8];
            #pragma unroll
            for (int f = 0; f < 8; ++f)
                r[f] = (L[0][c][f][lane] + L[1][c][f][lane]) +
                       (L[2][c][f][lane] + L[3][c][f][lane]);

            // softmax over 128 cols per row; D-frag: col=f*16+rlo, row=g*4+q
            #pragma unroll
            for (int q = 0; q < 4; ++q) {
                float lg[8];
                float mx = -1e30f;
                #pragma unroll
                for (int f = 0; f < 8; ++f) {
                    lg[f] = 2.f * r[f][q] - sq[f];
                    mx = fmaxf(mx, lg[f]);
                }
                #pragma unroll
                for (int msk = 1; msk < 16; msk <<= 1) mx = fmaxf(mx, __shfl_xor(mx, msk, 64));
                float sum = 0.f;
                #pragma unroll
                for (int f = 0; f < 8; ++f) {
                    float pv = __expf(lg[f] - mx);
                    lg[f] = pv;
                    sum += pv;
                }
                #pragma unroll
                for (int msk = 1; msk < 16; msk <<= 1) sum += __shfl_xor(sum, msk, 64);
                float inv = 1.f / sum;
                int row = row0 + (p * 2 + c) * 16 + g * 4 + q;
                #pragma unroll
                for (int f = 0; f < 8; ++f)
                    out[(size_t)row * N_CLS + f * 16 + rlo] = lg[f] * inv;
            }
        }
    }
}

extern "C" void kernel_launch(void* const* d_in, const int* in_sizes, int n_in,
                              void* d_out, int out_size, void* d_ws, size_t ws_size,
                              hipStream_t stream) {
    const float* e = (const float*)d_in[0];   // embeddings [N, D]
    const float* y = (const float*)d_in[1];   // y_true [N, C]
    float* out = (float*)d_out;               // [N, C]
    char* ws = (char*)d_ws;

    int*            cnt = (int*)(ws + CNT_OFF);
    float*          sqc = (float*)(ws + SQC_OFF);
    int*            rl  = (int*)(ws + RL_OFF);
    unsigned short* bHi = (unsigned short*)(ws + BHI_OFF);
    unsigned short* bLo = (unsigned short*)(ws + BLO_OFF);

    hipMemsetAsync(ws, 0, 32768, stream);  // padded cnt + sqc

    hipLaunchKernelGGL(k_label, dim3((N_ROWS * N_CLS / 4) / 256), dim3(256), 0, stream,
                       y, cnt, rl);
    hipLaunchKernelGGL(k_centroid, dim3(8, N_CLS), dim3(128), 0, stream,
                       e, cnt, rl, bHi, bLo, sqc);
    hipLaunchKernelGGL(k_gemm, dim3(N_ROWS / 64), dim3(256), 0, stream,
                       e, bHi, bLo, sqc, out);
}

// Round 6
// 134.455 us; speedup vs baseline: 1.0493x; 1.0493x over previous
//
#include <hip/hip_runtime.h>

// ProtoNet head: N=16384 rows, C=128 classes, D=1024 dims, fp32 in/out.
// out = softmax_c( 2*dot(e[n], cent[c]) - ||cent[c]^2 )  (sq_e dropped: softmax shift-invariant)
// cross term via split-bf16 MFMA: x=hi+lo; x*c ~= hi*chi + hi*clo + lo*chi  (K'=3072 bf16)

#define N_ROWS 16384
#define N_CLS  128
#define N_DIM  1024
#define CSTRIDE 32   // pad atomics: one counter per 128B cache line

// workspace layout (bytes); need ~672 KiB total
#define CNT_OFF 0         // int cnt[128*32]     (16 KiB)
#define SQC_OFF 16384     // float sqc[128*32]   (16 KiB)
#define RL_OFF  32768     // int rowlist[128*256] (128 KiB)
#define BHI_OFF 163840    // bf16 B-frags hi: 32 steps * 8 KiB/step = 256 KiB
#define BLO_OFF 425984    // bf16 B-frags lo: 256 KiB

typedef __attribute__((ext_vector_type(8))) short bf16x8;
typedef __attribute__((ext_vector_type(4))) float f32x4;

typedef const __attribute__((address_space(1))) void* gas1_cvp;
typedef __attribute__((address_space(3))) void* las3_vp;

__device__ __forceinline__ void gload16(const void* g, void* l) {
    // async global->LDS, 16B per lane; dest must be linear in lane order (it is)
    __builtin_amdgcn_global_load_lds((gas1_cvp)g, (las3_vp)l, 16, 0, 0);
}

// ---------------- kernel 1: labels -> rowlist + padded counts ----------------
__global__ void k_label(const float* __restrict__ y,
                        int* __restrict__ cnt,
                        int* __restrict__ rowlist) {
    int i = blockIdx.x * blockDim.x + threadIdx.x;   // float4 index over N*C/4
    float4 v = ((const float4*)y)[i];
    int base = i * 4;
    int row = base >> 7;          // / C
    int cb  = base & (N_CLS - 1); // % C
    if (v.x > 0.5f) { int s = atomicAdd(&cnt[(cb + 0) * CSTRIDE], 1); if (s < 256) rowlist[(cb + 0) * 256 + s] = row; }
    if (v.y > 0.5f) { int s = atomicAdd(&cnt[(cb + 1) * CSTRIDE], 1); if (s < 256) rowlist[(cb + 1) * 256 + s] = row; }
    if (v.z > 0.5f) { int s = atomicAdd(&cnt[(cb + 2) * CSTRIDE], 1); if (s < 256) rowlist[(cb + 2) * 256 + s] = row; }
    if (v.w > 0.5f) { int s = atomicAdd(&cnt[(cb + 3) * CSTRIDE], 1); if (s < 256) rowlist[(cb + 3) * 256 + s] = row; }
}

// ---- kernel 2: centroids -> packed bf16 hi/lo B-fragments + sq_c ----
// grid (8 d-chunks, 128 classes), 128 threads; thread owns (class c, dim d).
// B-frag for mfma_f32_16x16x32_bf16: elem j of lane l, step gs, col-frag f
//   = B[k = gs*32 + (l>>4)*8 + j][col = f*16 + (l&15)]
// Step gs's block (f,lane,j) is 8 KiB CONTIGUOUS -> linear LDS staging in k_gemm.
__global__ void k_centroid(const float* __restrict__ e,
                           const int* __restrict__ cnt,
                           const int* __restrict__ rowlist,
                           unsigned short* __restrict__ bHi,
                           unsigned short* __restrict__ bLo,
                           float* __restrict__ sqc) {
    int c  = blockIdx.y;
    int ch = blockIdx.x;
    int t  = threadIdx.x;
    int d  = ch * 128 + t;
    int n  = cnt[c * CSTRIDE];
    if (n > 256) n = 256;
    const int* rl = rowlist + c * 256;

    float acc = 0.f;
    int i = 0;
    // 16-deep MLP: ~32 KB/CU in flight vs ~22 KB needed at HBM latency
    for (; i + 16 <= n; i += 16) {
        float v[16];
        #pragma unroll
        for (int u = 0; u < 16; ++u) v[u] = e[(size_t)rl[i + u] * N_DIM + d];
        float s0 = ((v[0] + v[1]) + (v[2] + v[3])) + ((v[4] + v[5]) + (v[6] + v[7]));
        float s1 = ((v[8] + v[9]) + (v[10] + v[11])) + ((v[12] + v[13]) + (v[14] + v[15]));
        acc += s0 + s1;
    }
    for (; i < n; ++i) acc += e[(size_t)rl[i] * N_DIM + d];

    float val = (n > 0) ? acc / (float)n : 0.f;

    // split val = hi + lo (truncation split; the subtraction is exact)
    unsigned xb = __float_as_uint(val);
    unsigned short hv = (unsigned short)(xb >> 16);
    float hif = __uint_as_float(xb & 0xffff0000u);
    unsigned short lv = (unsigned short)(__float_as_uint(val - hif) >> 16);

    int gs = d >> 5;            // k-step
    int g  = (d >> 3) & 3;      // lane group
    int j  = d & 7;             // element within fragment
    int f  = c >> 4;            // col fragment
    int lb = g * 16 + (c & 15); // lane
    bHi[((gs * 8 + f) * 64 + lb) * 8 + j] = hv;
    bLo[((gs * 8 + f) * 64 + lb) * 8 + j] = lv;

    // ||centroid||^2 partial -> padded atomic (16 per class)
    float s = val * val;
    #pragma unroll
    for (int m = 1; m < 64; m <<= 1) s += __shfl_xor(s, m, 64);
    if ((t & 63) == 0) atomicAdd(&sqc[c * CSTRIDE], s);
}

// ------- kernel 3: split-bf16 MFMA GEMM + fused softmax --------
// 256 blocks x 256 thr. Wave (rt,h): rows blk*64+rt*32 (2 row-frags),
// K-half h (16 steps of 32 fp32-k). B double-buffer-staged into LDS via
// global_load_lds (no dest VGPRs -> nothing to serialize); A register
// ping-pong (4 loads/step). 48 MFMA/step/wave = 931-cyc shadow.
// After K-loop the 64 KiB staging LDS is reused as the combine buffer.
__device__ __forceinline__ void split8(const float4 a0, const float4 a1,
                                       bf16x8& hi, bf16x8& lo) {
    float v[8] = {a0.x, a0.y, a0.z, a0.w, a1.x, a1.y, a1.z, a1.w};
    #pragma unroll
    for (int j = 0; j < 8; ++j) {
        unsigned xb = __float_as_uint(v[j]);
        hi[j] = (short)(xb >> 16);
        float hif = __uint_as_float(xb & 0xffff0000u);
        lo[j] = (short)(__float_as_uint(v[j] - hif) >> 16);
    }
}

// stage step s (both h-halves, hi+lo) into buf: 4 chunks x 8 KiB, linear copy
__device__ __forceinline__ void stage_step(const char* bHiB, const char* bLoB,
                                           char* smem, int buf, int s, int tid) {
    #pragma unroll
    for (int hh = 0; hh < 2; ++hh) {
        const char* gh = bHiB + (size_t)(hh * 16 + s) * 8192;
        const char* gl = bLoB + (size_t)(hh * 16 + s) * 8192;
        char* dh = smem + ((buf * 2 + hh) * 2 + 0) * 8192;
        char* dl = smem + ((buf * 2 + hh) * 2 + 1) * 8192;
        #pragma unroll
        for (int part = 0; part < 2; ++part) {
            int off = tid * 16 + part * 4096;
            gload16(gh + off, dh + off);
            gload16(gl + off, dl + off);
        }
    }
}

__device__ __forceinline__ void read_b(const char* smem, int buf, int h, int lane,
                                       bf16x8 bh[8], bf16x8 bl[8]) {
    const bf16x8* ph = (const bf16x8*)(smem + ((buf * 2 + h) * 2 + 0) * 8192);
    const bf16x8* pl = (const bf16x8*)(smem + ((buf * 2 + h) * 2 + 1) * 8192);
    #pragma unroll
    for (int f = 0; f < 8; ++f) {
        bh[f] = ph[f * 64 + lane];
        bl[f] = pl[f * 64 + lane];
    }
}

__device__ __forceinline__ void load_a(const float* __restrict__ e,
                                       int row0, int rlo, int g, int gs,
                                       float4 a0[2], float4 a1[2]) {
    #pragma unroll
    for (int m = 0; m < 2; ++m) {
        const float* ap = e + (size_t)(row0 + m * 16 + rlo) * N_DIM + gs * 32 + g * 8;
        a0[m] = *(const float4*)ap;
        a1[m] = *(const float4*)(ap + 4);
    }
}

__device__ __forceinline__ void step_compute(const float4 a0[2], const float4 a1[2],
                                             const bf16x8 bh[8], const bf16x8 bl[8],
                                             f32x4 acc[2][8]) {
    bf16x8 ah[2], al[2];
    #pragma unroll
    for (int m = 0; m < 2; ++m) split8(a0[m], a1[m], ah[m], al[m]);
    #pragma unroll
    for (int f = 0; f < 8; ++f)
        #pragma unroll
        for (int m = 0; m < 2; ++m) {
            acc[m][f] = __builtin_amdgcn_mfma_f32_16x16x32_bf16(ah[m], bh[f], acc[m][f], 0, 0, 0);
            acc[m][f] = __builtin_amdgcn_mfma_f32_16x16x32_bf16(ah[m], bl[f], acc[m][f], 0, 0, 0);
            acc[m][f] = __builtin_amdgcn_mfma_f32_16x16x32_bf16(al[m], bh[f], acc[m][f], 0, 0, 0);
        }
}

__launch_bounds__(256, 1)
__global__ void k_gemm(const float* __restrict__ e,
                       const unsigned short* __restrict__ bHiU,
                       const unsigned short* __restrict__ bLoU,
                       const float* __restrict__ sqc,
                       float* __restrict__ out) {
    // 64 KiB: during K-loop = B staging (2 bufs x 2 h x hi/lo x 8 KiB);
    // after loop = combine buffer (32 KiB used).
    __shared__ f32x4 smem4[4096];
    char* smem = (char*)smem4;

    const char* bHiB = (const char*)bHiU;
    const char* bLoB = (const char*)bLoU;

    int tid  = threadIdx.x;
    int lane = tid & 63;
    int wid  = tid >> 6;
    int rt   = wid >> 1;        // row-tile within block
    int h    = wid & 1;         // K-half
    int row0 = blockIdx.x * 64 + rt * 32;
    int rlo  = lane & 15;
    int g    = lane >> 4;
    int gs0  = h * 16;

    f32x4 acc[2][8];
    #pragma unroll
    for (int m = 0; m < 2; ++m)
        #pragma unroll
        for (int f = 0; f < 8; ++f)
            acc[m][f] = (f32x4)(0.f);

    float4 a0A[2], a1A[2], a0B[2], a1B[2];

    // prologue: stage step 0 into buf 0; prefetch A step 0
    load_a(e, row0, rlo, g, gs0, a0A, a1A);
    stage_step(bHiB, bLoB, smem, 0, 0, tid);
    __syncthreads();   // implicit vmcnt(0): staging visible

    #pragma unroll 1
    for (int s2 = 0; s2 < 16; s2 += 2) {
        {   // even step s2 (buf 0): compute A-bufs, prefetch into B-bufs
            if (s2 + 1 < 16) {
                stage_step(bHiB, bLoB, smem, 1, s2 + 1, tid);
                load_a(e, row0, rlo, g, gs0 + s2 + 1, a0B, a1B);
            }
            bf16x8 bh[8], bl[8];
            read_b(smem, 0, h, lane, bh, bl);
            step_compute(a0A, a1A, bh, bl, acc);
            __syncthreads();   // drains staging of s2+1; all reads of buf0 done
        }
        {   // odd step s2+1 (buf 1)
            int s = s2 + 1;
            if (s + 1 < 16) {
                stage_step(bHiB, bLoB, smem, 0, s + 1, tid);
                load_a(e, row0, rlo, g, gs0 + s + 1, a0A, a1A);
            }
            bf16x8 bh[8], bl[8];
            read_b(smem, 1, h, lane, bh, bl);
            step_compute(a0B, a1B, bh, bl, acc);
            __syncthreads();
        }
    }

    // K-combine (reuse staging LDS, 32 KiB): h=1 dumps, h=0 adds.
    f32x4 (*L)[16][64] = (f32x4 (*)[16][64])smem4;
    if (h == 1) {
        #pragma unroll
        for (int m = 0; m < 2; ++m)
            #pragma unroll
            for (int f = 0; f < 8; ++f)
                L[rt][m * 8 + f][lane] = acc[m][f];
    }
    __syncthreads();
    if (h == 1) return;

    #pragma unroll
    for (int m = 0; m < 2; ++m)
        #pragma unroll
        for (int f = 0; f < 8; ++f)
            acc[m][f] += L[rt][m * 8 + f][lane];

    // epilogue: logits = 2*cross - sq_c ; softmax over 128 cols per row.
    // D-frag: col = f*16 + (lane&15), row = row0 + m*16 + (lane>>4)*4 + q.
    float sq[8];
    #pragma unroll
    for (int f = 0; f < 8; ++f) sq[f] = sqc[(f * 16 + rlo) * CSTRIDE];

    #pragma unroll
    for (int m = 0; m < 2; ++m)
        #pragma unroll
        for (int q = 0; q < 4; ++q) {
            float lg[8];
            float mx = -1e30f;
            #pragma unroll
            for (int f = 0; f < 8; ++f) {
                lg[f] = 2.f * acc[m][f][q] - sq[f];
                mx = fmaxf(mx, lg[f]);
            }
            #pragma unroll
            for (int msk = 1; msk < 16; msk <<= 1) mx = fmaxf(mx, __shfl_xor(mx, msk, 64));
            float sum = 0.f;
            #pragma unroll
            for (int f = 0; f < 8; ++f) {
                float pv = __expf(lg[f] - mx);
                lg[f] = pv;
                sum += pv;
            }
            #pragma unroll
            for (int msk = 1; msk < 16; msk <<= 1) sum += __shfl_xor(sum, msk, 64);
            float inv = 1.f / sum;
            int row = row0 + m * 16 + g * 4 + q;
            #pragma unroll
            for (int f = 0; f < 8; ++f)
                out[(size_t)row * N_CLS + f * 16 + rlo] = lg[f] * inv;
        }
}

extern "C" void kernel_launch(void* const* d_in, const int* in_sizes, int n_in,
                              void* d_out, int out_size, void* d_ws, size_t ws_size,
                              hipStream_t stream) {
    const float* e = (const float*)d_in[0];   // embeddings [N, D]
    const float* y = (const float*)d_in[1];   // y_true [N, C]
    float* out = (float*)d_out;               // [N, C]
    char* ws = (char*)d_ws;

    int*            cnt = (int*)(ws + CNT_OFF);
    float*          sqc = (float*)(ws + SQC_OFF);
    int*            rl  = (int*)(ws + RL_OFF);
    unsigned short* bHi = (unsigned short*)(ws + BHI_OFF);
    unsigned short* bLo = (unsigned short*)(ws + BLO_OFF);

    hipMemsetAsync(ws, 0, 32768, stream);  // padded cnt + sqc

    hipLaunchKernelGGL(k_label, dim3((N_ROWS * N_CLS / 4) / 256), dim3(256), 0, stream,
                       y, cnt, rl);
    hipLaunchKernelGGL(k_centroid, dim3(8, N_CLS), dim3(128), 0, stream,
                       e, cnt, rl, bHi, bLo, sqc);
    hipLaunchKernelGGL(k_gemm, dim3(N_ROWS / 64), dim3(256), 0, stream,
                       e, bHi, bLo, sqc, out);
}